// Round 6
// baseline (455.276 us; speedup 1.0000x reference)
//
#include <hip/hip_runtime.h>

typedef unsigned short u16;
typedef unsigned int   u32;
typedef __bf16 bf16_t;
typedef bf16_t bf16x8 __attribute__((ext_vector_type(8)));
typedef float  f32x4  __attribute__((ext_vector_type(4)));

__device__ __forceinline__ float b2f(u16 u){
  u32 x = ((u32)u) << 16;
  return __builtin_bit_cast(float, x);
}
__device__ __forceinline__ u16 f2b(float f){
  u32 u = __builtin_bit_cast(u32, f);
  u32 r = u + 0x7FFFu + ((u >> 16) & 1u);   // round-to-nearest-even
  return (u16)(r >> 16);
}

union V8 { uint4 q; u16 u[8]; };

// async global(16B/lane) -> LDS. dst wave-uniform; lane l lands at dst + l*16B.
__device__ __forceinline__ void gld16(const u16* gsrc, u16* ldst){
  __builtin_amdgcn_global_load_lds(
      (const __attribute__((address_space(1))) u32*)gsrc,
      (__attribute__((address_space(3))) u32*)ldst, 16, 0, 0);
}

// A-tile LDS XOR-swizzle (verified bit-identical in R5, conflicts -> 0):
//   stage slot (lane l): ((l&3) ^ ((l>>3)&3)) * 8    read slot: (quad ^ ((lr>>1)&3)) * 8
// B is NOT staged anymore (reuse factor within a block was 1 -> LDS round-trip was pure
// overhead); B fragments are loaded global->VGPR directly from the L2-resident weights.

// ---------- f32 -> bf16 convert (p1..p4 only now) ----------
struct CArgs { const float* src[4]; u16* dst[4]; int cnt[4]; };

__global__ __launch_bounds__(256) void convert_k(CArgs c){
  int z = blockIdx.z;
  int i8 = (blockIdx.x * 256 + threadIdx.x) * 8;
  if (i8 >= c.cnt[z]) return;
  const float* s = c.src[z] + i8;
  float4 a = *(const float4*)s;
  float4 b = *(const float4*)(s + 4);
  V8 o;
  o.u[0]=f2b(a.x); o.u[1]=f2b(a.y); o.u[2]=f2b(a.z); o.u[3]=f2b(a.w);
  o.u[4]=f2b(b.x); o.u[5]=f2b(b.y); o.u[6]=f2b(b.z); o.u[7]=f2b(b.w);
  *(uint4*)(c.dst[z] + i8) = o.q;
}

// ---------- transpose (z<5) + cbias/Gun-zero (z==5) ----------
struct TArgs { const float* src[5]; u16* dst[5]; int ncol[5]; };

__global__ __launch_bounds__(256) void transpose_k(TArgs t,
    const float* __restrict__ p1b, const float* __restrict__ p2b,
    const float* __restrict__ p3b, const float* __restrict__ p4b,
    const float* __restrict__ fw, const float* __restrict__ fb,
    float* __restrict__ cb, float* __restrict__ Gun)
{
  __shared__ u16 T[64][65];
  __shared__ float sb[512];
  int z = blockIdx.z;
  int tid = threadIdx.x;
  if (z == 5){
    if (blockIdx.x == 0 && blockIdx.y == 0){
      sb[tid]       = p1b[tid] + p2b[tid] + p3b[tid] + p4b[tid];
      sb[tid + 256] = p1b[tid+256] + p2b[tid+256] + p3b[tid+256] + p4b[tid+256];
      __syncthreads();
      float acc = 0.f;
      for (int j = 0; j < 512; j++) acc += sb[j] * fw[j*256 + tid];
      cb[tid] = acc + fb[tid];
    } else if (blockIdx.x >= 1 && blockIdx.x <= 4){
      int idx = ((blockIdx.x - 1)*8 + blockIdx.y)*256 + tid;
      Gun[idx] = 0.f;    // Gun is [2][8][512] = 8192 f32, must be zero each call
    }
    return;
  }
  int nc = t.ncol[z];
  int j0 = blockIdx.y * 64;
  if (j0 >= nc) return;
  int i0 = blockIdx.x * 64;
  const float* s = t.src[z];
  u16* d = t.dst[z];
  #pragma unroll
  for (int rep = 0; rep < 16; rep++){
    int lin = rep*256 + tid;
    int r = lin >> 6, c = lin & 63;
    T[c][r] = f2b(s[(size_t)(i0 + r) * nc + j0 + c]);
  }
  __syncthreads();
  #pragma unroll
  for (int rep = 0; rep < 16; rep++){
    int lin = rep*256 + tid;
    int r = lin >> 6, c = lin & 63;
    d[(size_t)(j0 + r) * 512 + i0 + c] = T[r][c];
  }
}

// ------------- fused projection + bias + row-l2norm + Araw + Gun accumulation -------------
// grid (512, 2, 2): x = 64-row m-block, y: 0=q (writes Q, Araw, Gun), 1=k; z: 0=I, 1=M.
// LDS carries ONLY the shared A tile (4x reuse). B fragments load global->VGPR per step
// (L2-resident weights; compiler emits exact counted vmcnt for them). A f32 prefetch at
// distance 2 rides across the raw lgkmcnt(0)+s_barrier (T4: loads in flight across barriers).
__global__ __launch_bounds__(256, 2) void proj_k(
    const float* __restrict__ XI, const float* __restrict__ XM,
    const u16* __restrict__ WTI, const u16* __restrict__ WTM,  // [1024][512]: rows 0-511 wq^T, 512-1023 wk^T
    const float* __restrict__ bqI, const float* __restrict__ bkI,
    const float* __restrict__ bqM, const float* __restrict__ bkM,
    const float* __restrict__ wgI, const float* __restrict__ wgM,
    u16* __restrict__ qI, u16* __restrict__ kI,
    u16* __restrict__ qM, u16* __restrict__ kM,
    float* __restrict__ Araw, float* __restrict__ Gun)
{
  const int tid = threadIdx.x, l = tid & 63, w = tid >> 6;
  const int m0 = blockIdx.x * 64;
  const int y  = blockIdx.y, zi = blockIdx.z;
  __shared__ __align__(16) u16 As[2][64*32];     // 8 KB shared A tile (bf16), dbuf, swizzled
  const int lr = l & 15, quad = l >> 4;
  const int swz8 = ((l & 3) ^ ((l >> 3) & 3)) * 8;     // A stage slot
  const int aqs8 = (quad ^ ((lr >> 1) & 3)) * 8;       // A read slot
  const int wn = w * 128;

  const float* X  = zi ? XM : XI;
  const u16* Wb = (zi ? WTM : WTI) + (size_t)y * 512 * 512 + (size_t)wn * 512;
  const float* bias = y ? (zi ? bkM : bkI) : (zi ? bqM : bqI);
  const float* wg   = zi ? wgM : wgI;
  u16* OUT = y ? (zi ? kM : kI) : (zi ? qM : qI);

  // A staging map: lane l -> row w*16 + l/4, global k-seg (l&3)*8 (32B contiguous)
  const int arow = w*16 + (l >> 2);
  const int aks  = (l & 3) * 8;
  const float* aptr = X + (size_t)(m0 + arow)*512 + aks;

  f32x4 acc[4][8] = {};
  float4 s0a, s0b, s1a, s1b;   // two rotating A-stage reg sets

  // ---- prologue: a(0), a(1) in flight; convert a(0) -> As[0] ----
  s0a = *(const float4*)(aptr);
  s0b = *(const float4*)(aptr + 4);
  s1a = *(const float4*)(aptr + 32);
  s1b = *(const float4*)(aptr + 36);
  {
    V8 o;   // compiler inserts counted vmcnt(2) here (a(1) stays in flight)
    o.u[0]=f2b(s0a.x); o.u[1]=f2b(s0a.y); o.u[2]=f2b(s0a.z); o.u[3]=f2b(s0a.w);
    o.u[4]=f2b(s0b.x); o.u[5]=f2b(s0b.y); o.u[6]=f2b(s0b.z); o.u[7]=f2b(s0b.w);
    *(uint4*)&As[0][arow*32 + swz8] = o.q;
  }
  asm volatile("s_waitcnt lgkmcnt(0)" ::: "memory");
  __builtin_amdgcn_sched_barrier(0);
  __builtin_amdgcn_s_barrier();

// step t body. P = t&1 (reads As[P], writes As[P^1]). KT = t*32 (B k-offset, loaded direct).
// CV = regs holding a(t+1) to convert; LD = regs receiving a(t+2) (KA = (t+2)*32).
#define PBODY(P, CV0, CV1, LD0, LD1, KA, KT, DOLOAD, DOBAR) do{                            \
    bf16x8 bF[8];                                                                          \
    _Pragma("unroll")                                                                      \
    for (int nt = 0; nt < 8; nt++)                                                         \
      bF[nt] = *(const bf16x8*)&Wb[(size_t)(nt*16 + lr)*512 + (KT) + quad*8];              \
    bf16x8 aF[4];                                                                          \
    _Pragma("unroll")                                                                      \
    for (int mt = 0; mt < 4; mt++)                                                         \
      aF[mt] = *(const bf16x8*)&As[(P)][(mt*16 + lr)*32 + aqs8];                           \
    if (DOLOAD){                                                                           \
      LD0 = *(const float4*)(aptr + (KA));                                                 \
      LD1 = *(const float4*)(aptr + (KA) + 4);                                             \
    }                                                                                      \
    if (DOBAR){ V8 o;                                                                      \
      o.u[0]=f2b((CV0).x); o.u[1]=f2b((CV0).y); o.u[2]=f2b((CV0).z); o.u[3]=f2b((CV0).w); \
      o.u[4]=f2b((CV1).x); o.u[5]=f2b((CV1).y); o.u[6]=f2b((CV1).z); o.u[7]=f2b((CV1).w); \
      *(uint4*)&As[(P)^1][arow*32 + swz8] = o.q; }                                         \
    __builtin_amdgcn_s_setprio(1);                                                         \
    _Pragma("unroll")                                                                      \
    for (int mt = 0; mt < 4; mt++){                                                        \
      _Pragma("unroll")                                                                    \
      for (int nt = 0; nt < 8; nt++)                                                       \
        acc[mt][nt] = __builtin_amdgcn_mfma_f32_16x16x32_bf16(aF[mt], bF[nt], acc[mt][nt], 0, 0, 0); \
    }                                                                                      \
    __builtin_amdgcn_s_setprio(0);                                                         \
    if (DOBAR){                                                                            \
      asm volatile("s_waitcnt lgkmcnt(0)" ::: "memory");                                   \
      __builtin_amdgcn_sched_barrier(0);                                                   \
      __builtin_amdgcn_s_barrier();                                                        \
    }                                                                                      \
  } while(0)

  for (int tt = 0; tt < 7; ++tt){
    PBODY(0, s1a, s1b, s0a, s0b, (2*tt+2)*32, (2*tt)*32,   1, 1);   // t = 2tt
    PBODY(1, s0a, s0b, s1a, s1b, (2*tt+3)*32, (2*tt+1)*32, 1, 1);   // t = 2tt+1
  }
  PBODY(0, s1a, s1b, s0a, s0b, 0, 448, 0, 1);                       // t = 14 (converts a(15))
  PBODY(1, s0a, s0b, s1a, s1b, 0, 480, 0, 0);                       // t = 15 (bare)
#undef PBODY

  // ---- epilogue ----
  float wgv[8];
  if (y == 0){
    #pragma unroll
    for (int nt = 0; nt < 8; nt++) wgv[nt] = wg[wn + nt*16 + lr];
  }
  #pragma unroll
  for (int nt = 0; nt < 8; nt++){
    float bcol = bias[wn + nt*16 + lr];
    #pragma unroll
    for (int mt = 0; mt < 4; mt++)
      #pragma unroll
      for (int r = 0; r < 4; r++)
        acc[mt][nt][r] += bcol;
  }
  float ss[4][4], dq[4][4];
  #pragma unroll
  for (int mt = 0; mt < 4; mt++)
    #pragma unroll
    for (int r = 0; r < 4; r++){
      float s = 0.f, d = 0.f;
      #pragma unroll
      for (int nt = 0; nt < 8; nt++){
        float v = acc[mt][nt][r];
        s += v*v;
        if (y == 0) d += v * wgv[nt];
      }
      ss[mt][r] = s; dq[mt][r] = d;
    }
  #pragma unroll
  for (int off = 1; off < 16; off <<= 1){
    #pragma unroll
    for (int mt = 0; mt < 4; mt++)
      #pragma unroll
      for (int r = 0; r < 4; r++){
        ss[mt][r] += __shfl_xor(ss[mt][r], off, 64);
        if (y == 0) dq[mt][r] += __shfl_xor(dq[mt][r], off, 64);
      }
  }
  __syncthreads();                 // As dead -> reuse as f32 scratch
  float* red    = (float*)As;      // [4][64]
  float* red2   = red + 256;       // [4][64]
  float* rnS    = red2 + 256;      // [64]
  float* araw_s = rnS + 64;        // [64]  (total 2560B < 8KB As)
  if (lr == 0){
    #pragma unroll
    for (int mt = 0; mt < 4; mt++)
      #pragma unroll
      for (int r = 0; r < 4; r++){
        int row = mt*16 + quad*4 + r;
        red[w*64 + row] = ss[mt][r];
        if (y == 0) red2[w*64 + row] = dq[mt][r];
      }
  }
  __syncthreads();
  if (tid < 64){
    float t2 = red[tid] + red[64+tid] + red[128+tid] + red[192+tid];
    float rn = 1.f / fmaxf(sqrtf(t2), 1e-12f);
    rnS[tid] = rn;
    if (y == 0){
      float d = red2[tid] + red2[64+tid] + red2[128+tid] + red2[192+tid];
      float a = d * rn * 0.0625f;               // SCALE = 1/16
      araw_s[tid] = a;
      Araw[zi*32768 + m0 + tid] = a;
    }
  }
  __syncthreads();
  float part[8] = {};
  #pragma unroll
  for (int mt = 0; mt < 4; mt++){
    f32x4 rn4 = *(const f32x4*)&rnS[mt*16 + quad*4];
    #pragma unroll
    for (int r = 0; r < 4; r++){
      float aw = (y == 0) ? araw_s[mt*16 + quad*4 + r] : 0.f;
      #pragma unroll
      for (int nt = 0; nt < 8; nt++){
        float v = acc[mt][nt][r] * rn4[r];
        OUT[(size_t)(m0 + mt*16 + quad*4 + r)*512 + wn + nt*16 + lr] = f2b(v);
        if (y == 0) part[nt] += aw * v;
      }
    }
  }
  if (y == 0){
    #pragma unroll
    for (int nt = 0; nt < 8; nt++){
      part[nt] += __shfl_xor(part[nt], 16, 64);
      part[nt] += __shfl_xor(part[nt], 32, 64);
    }
    if (quad == 0){
      int bb = blockIdx.x >> 6;   // 64 rows/block, 4096 rows/batch
      #pragma unroll
      for (int nt = 0; nt < 8; nt++)
        atomicAdd(&Gun[((size_t)zi*8 + bb)*512 + wn + nt*16 + lr], part[nt]);
    }
  }
}

// ------------- MFMA GEMM, 128x128 tile, BK=32: A-only LDS ring (dist-3, vmcnt(4)), B direct ---
// LDS = 4 x (128 rows x 32 k) A buffers (32 KB, swizzled). B fragments load global->VGPR
// (L2-resident). In-flight A gld16 at the hand vmcnt: tiles t+1..t+3 = 6; wait t+1 -> vmcnt(4).
// bF loads are consumed by MFMA before that point (compiler-counted), so they don't pollute it.
// MODE 1 (SMALL): C = A0 @ BT_z^T      K=512, N=512, z-batched over 4 slabs -> pfT (bf16)
// MODE 2 (FINAL): C = [kI|kM|qI|qM] @ WT[b]^T + cb  K=2048, N=256 -> Cf (f32)
template<int MODE>
__global__ __launch_bounds__(256, 3) void gemm2_k(
    const u16* __restrict__ A0, const u16* __restrict__ A1,
    const u16* __restrict__ A2, const u16* __restrict__ A3,
    const u16* __restrict__ BT,
    const float* __restrict__ cb,
    u16* __restrict__ Cq, float* __restrict__ Cf)
{
  constexpr int KTOT = (MODE == 2) ? 2048 : 512;
  constexpr int NT   = KTOT / 32;
  const int tid = threadIdx.x, l = tid & 63, w = tid >> 6;
  const int m0 = blockIdx.x * 128, n0 = blockIdx.y * 128;
  __shared__ __align__(16) u16 SA[4][4096];   // 32 KB: A ring [buf][128 rows x 32 k], swizzled
  f32x4 acc[4][4] = {};
  const int wm = (w >> 1) * 64, wn = (w & 1) * 64;
  const int lr = l & 15, quad = l >> 4;
  const int srow = l >> 2;
  const int swz8 = ((l & 3) ^ ((l >> 3) & 3)) * 8;     // A stage slot (global pre-swizzle)
  const int aqs8 = (quad ^ ((lr >> 1) & 3)) * 8;       // A read slot

  const u16* Bbase = BT;
  u16* Cqb = Cq;
  if constexpr (MODE == 2)
    Bbase = BT + (size_t)(m0 >> 12) * 256 * 2048;   // per-batch folded weights
  if constexpr (MODE == 1){
    Bbase = BT + (size_t)blockIdx.z * 262144;       // pcat slab
    Cqb   = Cq + (size_t)blockIdx.z * 131072;       // pfT slab
  }
  const u16* Bb = Bbase + (size_t)(n0 + wn) * KTOT; // this wave's B row base

  // stage A tile at k-offset kk into ring buffer buf (2 gld16/wave), global col pre-swizzled
  auto stageA = [&](int kk, int buf) __attribute__((always_inline)) {
    const u16* Ab; int kloc;
    if constexpr (MODE == 2){
      int which = kk >> 9; kloc = kk & 511;
      Ab = (which == 0) ? A0 : (which == 1) ? A1 : (which == 2) ? A2 : A3;
    } else { Ab = A0; kloc = kk; }
    #pragma unroll
    for (int i = 0; i < 2; i++){
      int r = w*32 + i*16 + srow;
      gld16(Ab + (size_t)(m0 + r) * 512 + kloc + swz8, &SA[buf][(w*2 + i)*512]);
    }
  };

  // ---- prologue: stage A tiles 0,1,2 ----
  stageA(0, 0);
  stageA(32, 1);
  stageA(64, 2);
  asm volatile("s_waitcnt vmcnt(4)" ::: "memory");   // tile 0 landed; 1,2 in flight
  __builtin_amdgcn_sched_barrier(0);
  __builtin_amdgcn_s_barrier();

  for (int t = 0; t < NT; ++t){
    bf16x8 bF[4];
    #pragma unroll
    for (int nt = 0; nt < 4; nt++)
      bF[nt] = *(const bf16x8*)&Bb[(size_t)(nt*16 + lr)*KTOT + t*32 + quad*8];
    bf16x8 aF[4];
    #pragma unroll
    for (int mt = 0; mt < 4; mt++)
      aF[mt] = *(const bf16x8*)&SA[t & 3][(wm + mt*16 + lr)*32 + aqs8];
    if (t < NT - 1){
      int kn = (t + 3 < NT) ? (t + 3)*32 : 0;        // clamped dummy keeps counts uniform
      stageA(kn, (t + 3) & 3);
    }
    __builtin_amdgcn_s_setprio(1);
    #pragma unroll
    for (int mt = 0; mt < 4; mt++){
      #pragma unroll
      for (int nt = 0; nt < 4; nt++)
        acc[mt][nt] = __builtin_amdgcn_mfma_f32_16x16x32_bf16(aF[mt], bF[nt], acc[mt][nt], 0, 0, 0);
    }
    __builtin_amdgcn_s_setprio(0);
    if (t < NT - 1){
      __builtin_amdgcn_sched_barrier(0);
      asm volatile("s_waitcnt vmcnt(4)" ::: "memory"); // A tile t+1 landed; t+2,t+3 in flight
      __builtin_amdgcn_sched_barrier(0);
      __builtin_amdgcn_s_barrier();
    }
  }
  asm volatile("s_waitcnt vmcnt(0)" ::: "memory");     // drain dummy gld16 before LDS dealloc

  #pragma unroll
  for (int nt = 0; nt < 4; nt++){
    int col = n0 + wn + nt*16 + lr;
    #pragma unroll
    for (int mt = 0; mt < 4; mt++){
      int row0 = m0 + wm + mt*16 + quad*4;
      #pragma unroll
      for (int r = 0; r < 4; r++){
        int row = row0 + r;
        float v = acc[mt][nt][r];
        if constexpr (MODE == 1){
          Cqb[(size_t)row*512 + col] = f2b(v);
        } else {
          Cf[(size_t)row*256 + col] = v + cb[col];
        }
      }
    }
  }
}

// -------- rA[i] = 1/max(||Araw_i||, eps), i = wsel*8 + b --------
__global__ __launch_bounds__(256) void ranorm_k(const float* __restrict__ Araw,
                                                float* __restrict__ rA){
  int idx = blockIdx.x;               // 0..15
  const float* A = Araw + idx*4096;
  int tid = threadIdx.x, l = tid & 63, w = tid >> 6;
  float ss = 0.f;
  for (int i = tid; i < 4096; i += 256){ float a = A[i]; ss += a*a; }
  #pragma unroll
  for (int off = 32; off > 0; off >>= 1) ss += __shfl_xor(ss, off, 64);
  __shared__ float red[4];
  if (l == 0) red[w] = ss;
  __syncthreads();
  if (tid == 0)
    rA[idx] = 1.f / fmaxf(sqrtf(red[0] + red[1] + red[2] + red[3]), 1e-12f);
}

// -------- WT[b][o][k]: k<512: G_I.pf1+G_M.pf4 (kI); <1024: G_I.pf2+G_M.pf3 (kM); else fT (qI+qM) --------
__global__ __launch_bounds__(256) void weff_k(
    const u16* __restrict__ pfT, const u16* __restrict__ fT,
    const float* __restrict__ Gun, const float* __restrict__ rA,
    u16* __restrict__ WT)
{
  int b = blockIdx.x, o = blockIdx.y, tid = threadIdx.x;
  int k0 = tid * 8;
  V8 out;
  if (k0 < 1024){
    int kk = k0 & 511;
    const u16* pa = pfT + ((k0 < 512) ? 0      : 131072) + o*512 + kk;  // pf1 / pf2
    const u16* pb = pfT + ((k0 < 512) ? 393216 : 262144) + o*512 + kk;  // pf4 / pf3
    float rI = rA[b], rM = rA[8 + b];
    const float* gI = Gun + b*512 + kk;
    const float* gM = Gun + 4096 + b*512 + kk;
    V8 Pa, Pb; Pa.q = *(const uint4*)pa; Pb.q = *(const uint4*)pb;
    float4 gi0 = *(const float4*)gI, gi1 = *(const float4*)(gI+4);
    float4 gm0 = *(const float4*)gM, gm1 = *(const float4*)(gM+4);
    float gi[8] = {gi0.x,gi0.y,gi0.z,gi0.w,gi1.x,gi1.y,gi1.z,gi1.w};
    float gm[8] = {gm0.x,gm0.y,gm0.z,gm0.w,gm1.x,gm1.y,gm1.z,gm1.w};
    #pragma unroll
    for (int j = 0; j < 8; j++)
      out.u[j] = f2b(rI*gi[j]*b2f(Pa.u[j]) + rM*gm[j]*b2f(Pb.u[j]));
  } else {
    out.q = *(const uint4*)(fT + o*512 + (k0 & 511));
  }
  *(uint4*)(WT + ((size_t)b*256 + o)*2048 + k0) = out.q;
}

extern "C" void kernel_launch(void* const* d_in, const int* in_sizes, int n_in,
                              void* d_out, int out_size, void* d_ws, size_t ws_size,
                              hipStream_t stream)
{
  const float* x_I  = (const float*)d_in[0];
  const float* x_M  = (const float*)d_in[1];
  const float* wq_I = (const float*)d_in[2];
  const float* bq_I = (const float*)d_in[3];
  const float* wk_I = (const float*)d_in[4];
  const float* bk_I = (const float*)d_in[5];
  const float* wq_M = (const float*)d_in[6];
  const float* bq_M = (const float*)d_in[7];
  const float* wk_M = (const float*)d_in[8];
  const float* bk_M = (const float*)d_in[9];
  const float* wg_I = (const float*)d_in[10];
  const float* wg_M = (const float*)d_in[11];
  const float* p1_w = (const float*)d_in[12];
  const float* p1_b = (const float*)d_in[13];
  const float* p2_w = (const float*)d_in[14];
  const float* p2_b = (const float*)d_in[15];
  const float* p3_w = (const float*)d_in[16];
  const float* p3_b = (const float*)d_in[17];
  const float* p4_w = (const float*)d_in[18];
  const float* p4_b = (const float*)d_in[19];
  const float* f_w  = (const float*)d_in[20];
  const float* f_b  = (const float*)d_in[21];

  char* ws = (char*)d_ws;
  u16*  wqkT_I = (u16*)(ws + 0);          // [1024][512] bf16
  u16*  wqkT_M = (u16*)(ws + 1048576);    // [1024][512]
  u16*  fT     = (u16*)(ws + 2097152);    // [256][512]
  u16*  pcat   = (u16*)(ws + 2359296);    // [4][512][512] bf16 straight
  u16*  pfT    = (u16*)(ws + 4456448);    // [4][256][512] bf16 (131072 elems/slab)
  u16*  WT     = (u16*)(ws + 5505024);    // [8][256][2048] bf16
  float* cb    = (float*)(ws + 13893632); // [256]
  float* Araw  = (float*)(ws + 13894656); // [2][32768]
  float* rA    = (float*)(ws + 14156800); // [16]
  float* Gun   = (float*)(ws + 14157056); // [2][8][512]
  u16*  qIb    = (u16*)(ws + 14189824);   // [32768][512] bf16 each
  u16*  kIb    = (u16*)(ws + 47744256);
  u16*  qMb    = (u16*)(ws + 81298688);
  u16*  kMb    = (u16*)(ws + 114853120);

  // --- 1: p1..p4 f32->bf16 ---
  CArgs c;
  const float* csrc[4] = {p1_w, p2_w, p3_w, p4_w};
  u16* cdst[4] = {pcat, pcat + 262144, pcat + 524288, pcat + 786432};
  for (int i = 0; i < 4; i++){ c.src[i] = csrc[i]; c.dst[i] = cdst[i]; c.cnt[i] = 262144; }
  convert_k<<<dim3(128,1,4), 256, 0, stream>>>(c);

  // --- 2: weight transposes + cbias + Gun zero ---
  TArgs t;
  const float* tsrc[5] = {wq_I, wk_I, wq_M, wk_M, f_w};
  u16* tdst[5] = {wqkT_I, wqkT_I + 262144, wqkT_M, wqkT_M + 262144, fT};
  int tnc[5] = {512, 512, 512, 512, 256};
  for (int i = 0; i < 5; i++){ t.src[i] = tsrc[i]; t.dst[i] = tdst[i]; t.ncol[i] = tnc[i]; }
  transpose_k<<<dim3(8,8,6), 256, 0, stream>>>(t, p1_b, p2_b, p3_b, p4_b, f_w, f_b, cb, Gun);

  // --- 3: pfT_i[o][d] = sum_j f_w[j][o] p_i[d][j] ---
  gemm2_k<1><<<dim3(2,4,4), 256, 0, stream>>>(fT, nullptr, nullptr, nullptr,
      pcat, nullptr, pfT, nullptr);

  // --- 4: fused projection + norm + Araw + Gun (both inputs, one launch) ---
  proj_k<<<dim3(512,2,2), 256, 0, stream>>>(x_I, x_M, wqkT_I, wqkT_M,
      bq_I, bk_I, bq_M, bk_M, wg_I, wg_M, qIb, kIb, qMb, kMb, Araw, Gun);

  // --- 5: rA ---
  ranorm_k<<<16, 256, 0, stream>>>(Araw, rA);

  // --- 6: fold G into effective weights ---
  weff_k<<<dim3(8,256), 256, 0, stream>>>(pfT, fT, Gun, rA, WT);

  // --- 7: out = [kI|kM|qI|qM] @ WT[b]^T + cb ---
  gemm2_k<2><<<dim3(256,2), 256, 0, stream>>>(kIb, kMb, qIb, qMb,
      WT, cb, nullptr, (float*)d_out);
}

// Round 7
// 374.114 us; speedup vs baseline: 1.2169x; 1.2169x over previous
//
#include <hip/hip_runtime.h>

typedef unsigned short u16;
typedef unsigned int   u32;
typedef __bf16 bf16_t;
typedef bf16_t bf16x8 __attribute__((ext_vector_type(8)));
typedef float  f32x4  __attribute__((ext_vector_type(4)));

__device__ __forceinline__ float b2f(u16 u){
  u32 x = ((u32)u) << 16;
  return __builtin_bit_cast(float, x);
}
__device__ __forceinline__ u16 f2b(float f){
  u32 u = __builtin_bit_cast(u32, f);
  u32 r = u + 0x7FFFu + ((u >> 16) & 1u);   // round-to-nearest-even
  return (u16)(r >> 16);
}

union V8 { uint4 q; u16 u[8]; };

// async global(16B/lane) -> LDS. dst wave-uniform; lane l lands at dst + l*16B.
__device__ __forceinline__ void gld16(const u16* gsrc, u16* ldst){
  __builtin_amdgcn_global_load_lds(
      (const __attribute__((address_space(1))) u32*)gsrc,
      (__attribute__((address_space(3))) u32*)ldst, 16, 0, 0);
}

// T2 LDS XOR-swizzle (verified bit-identical, conflicts 6.29M -> 0 in R5):
//   stage slot (lane l): ((l&3) ^ ((l>>3)&3)) * 8    read slot: (quad ^ ((lr>>1)&3)) * 8

struct CArgs { const float* src[4]; u16* dst[4]; };

// ---------- transpose (z<5) + cbias/Gun-zero (z==5) + p1..p4 f32->bf16 convert (z>=6) ----------
struct TArgs { const float* src[5]; u16* dst[5]; int ncol[5]; };

__global__ __launch_bounds__(256) void transpose_k(TArgs t, CArgs c,
    const float* __restrict__ p1b, const float* __restrict__ p2b,
    const float* __restrict__ p3b, const float* __restrict__ p4b,
    const float* __restrict__ fw, const float* __restrict__ fb,
    float* __restrict__ cb, float* __restrict__ Gun)
{
  __shared__ u16 T[64][65];
  __shared__ float sb[512];
  int z = blockIdx.z;
  int tid = threadIdx.x;
  if (z >= 6){                       // convert p_{z-6}: 262144 f32 -> bf16, 16/thread
    int zz = z - 6;
    int i16 = ((blockIdx.x*8 + blockIdx.y)*256 + tid) * 16;
    const float* s = c.src[zz] + i16;
    u16* d = c.dst[zz] + i16;
    #pragma unroll
    for (int h = 0; h < 2; h++){
      float4 a = *(const float4*)(s + h*8);
      float4 b = *(const float4*)(s + h*8 + 4);
      V8 o;
      o.u[0]=f2b(a.x); o.u[1]=f2b(a.y); o.u[2]=f2b(a.z); o.u[3]=f2b(a.w);
      o.u[4]=f2b(b.x); o.u[5]=f2b(b.y); o.u[6]=f2b(b.z); o.u[7]=f2b(b.w);
      *(uint4*)(d + h*8) = o.q;
    }
    return;
  }
  if (z == 5){
    if (blockIdx.x == 0 && blockIdx.y == 0){
      sb[tid]       = p1b[tid] + p2b[tid] + p3b[tid] + p4b[tid];
      sb[tid + 256] = p1b[tid+256] + p2b[tid+256] + p3b[tid+256] + p4b[tid+256];
      __syncthreads();
      float acc = 0.f;
      for (int j = 0; j < 512; j++) acc += sb[j] * fw[j*256 + tid];
      cb[tid] = acc + fb[tid];
    } else if (blockIdx.x >= 1 && blockIdx.x <= 4){
      int idx = ((blockIdx.x - 1)*8 + blockIdx.y)*256 + tid;
      Gun[idx] = 0.f;    // Gun is [2][8][512] = 8192 f32, must be zero each call
    }
    return;
  }
  int nc = t.ncol[z];
  int j0 = blockIdx.y * 64;
  if (j0 >= nc) return;
  int i0 = blockIdx.x * 64;
  const float* s = t.src[z];
  u16* d = t.dst[z];
  #pragma unroll
  for (int rep = 0; rep < 16; rep++){
    int lin = rep*256 + tid;
    int r = lin >> 6, cc = lin & 63;
    T[cc][r] = f2b(s[(size_t)(i0 + r) * nc + j0 + cc]);
  }
  __syncthreads();
  #pragma unroll
  for (int rep = 0; rep < 16; rep++){
    int lin = rep*256 + tid;
    int r = lin >> 6, cc = lin & 63;
    d[(size_t)(j0 + r) * 512 + i0 + cc] = T[r][cc];
  }
}

// ------------- fused projection + bias + row-l2norm + Araw + Gun accumulation -------------
// grid (512, 2, 2): x = 64-row m-block, y: 0=q (writes Q, Araw, Gun), 1=k; z: 0=I, 1=M.
// VERBATIM R5 (verified 153 us, bank-conflicts 0): counted-vmcnt pipeline + T2 swizzle.
__global__ __launch_bounds__(256, 2) void proj_k(
    const float* __restrict__ XI, const float* __restrict__ XM,
    const u16* __restrict__ WTI, const u16* __restrict__ WTM,  // [1024][512]: rows 0-511 wq^T, 512-1023 wk^T
    const float* __restrict__ bqI, const float* __restrict__ bkI,
    const float* __restrict__ bqM, const float* __restrict__ bkM,
    const float* __restrict__ wgI, const float* __restrict__ wgM,
    u16* __restrict__ qI, u16* __restrict__ kI,
    u16* __restrict__ qM, u16* __restrict__ kM,
    float* __restrict__ Araw, float* __restrict__ Gun)
{
  const int tid = threadIdx.x, l = tid & 63, w = tid >> 6;
  const int m0 = blockIdx.x * 64;
  const int y  = blockIdx.y, zi = blockIdx.z;
  __shared__ __align__(16) u16 As[2][64*32];     // 8 KB shared A tile (bf16), dbuf, swizzled
  __shared__ __align__(16) u16 Bs[2][4][4096];   // 64 KB wave-private B slabs, dbuf, swizzled
  const int lr = l & 15, quad = l >> 4;
  const int srow = l >> 2;
  const int swz8 = ((l & 3) ^ ((l >> 3) & 3)) * 8;     // stage slot (global pre-swizzle / A ds_write)
  const int aqs8 = (quad ^ ((lr >> 1) & 3)) * 8;       // read slot (swizzled ds_read)
  const int wn = w * 128;

  const float* X  = zi ? XM : XI;
  const u16* Wbase = (zi ? WTM : WTI) + (size_t)y * 512 * 512 + (size_t)wn * 512;
  const float* bias = y ? (zi ? bkM : bkI) : (zi ? bqM : bqI);
  const float* wg   = zi ? wgM : wgI;
  u16* OUT = y ? (zi ? kM : kI) : (zi ? qM : qI);

  // A staging map: lane l -> row w*16 + l/4; global k-seg stays (l&3)*8, LDS slot is swizzled
  const int arow = w*16 + (l >> 2);
  const int aks  = (l & 3) * 8;
  const float* aptr = X + (size_t)(m0 + arow)*512 + aks;

  f32x4 acc[4][8] = {};
  float4 s0a, s0b, s1a, s1b;   // two rotating A-stage reg sets

  // ---- prologue ----
  s0a = *(const float4*)(aptr);          // a(0)
  s0b = *(const float4*)(aptr + 4);
  __builtin_amdgcn_sched_barrier(0);
  #pragma unroll
  for (int i = 0; i < 8; i++)            // B(0), global col pre-swizzled
    gld16(Wbase + (size_t)(i*16 + srow)*512 + swz8, &Bs[0][w][i*512]);
  __builtin_amdgcn_sched_barrier(0);
  s1a = *(const float4*)(aptr + 32);     // a(1)
  s1b = *(const float4*)(aptr + 36);
  __builtin_amdgcn_sched_barrier(0);
  {
    V8 o;                                // convert a(0) -> As[0] at swizzled slot
    o.u[0]=f2b(s0a.x); o.u[1]=f2b(s0a.y); o.u[2]=f2b(s0a.z); o.u[3]=f2b(s0a.w);
    o.u[4]=f2b(s0b.x); o.u[5]=f2b(s0b.y); o.u[6]=f2b(s0b.z); o.u[7]=f2b(s0b.w);
    *(uint4*)&As[0][arow*32 + swz8] = o.q;
  }
  asm volatile("s_waitcnt vmcnt(2)" ::: "memory");   // drain B(0); a(1) stays in flight
  asm volatile("s_waitcnt lgkmcnt(0)" ::: "memory"); // As[0] visible
  __builtin_amdgcn_sched_barrier(0);
  __builtin_amdgcn_s_barrier();

// step body. P: buffer parity (reads [P], writes [P^1]). CV = regs holding a(t+1) to convert.
// LD = regs to receive a(t+2). KB = k-offset of B(t+1). Tail wait VMC: 2 steady, 0 at t=14.
#define PBODY(P, CV0, CV1, LD0, LD1, KA, KB, DOLOAD, VMC) do{                              \
    bf16x8 aF[4], bF[8];                                                                   \
    _Pragma("unroll")                                                                      \
    for (int mt = 0; mt < 4; mt++)                                                         \
      aF[mt] = *(const bf16x8*)&As[(P)][(mt*16 + lr)*32 + aqs8];                           \
    _Pragma("unroll")                                                                      \
    for (int nt = 0; nt < 8; nt++)                                                         \
      bF[nt] = *(const bf16x8*)&Bs[(P)][w][(nt*16 + lr)*32 + aqs8];                        \
    __builtin_amdgcn_sched_barrier(0);                                                     \
    _Pragma("unroll")                                                                      \
    for (int i = 0; i < 8; i++)                                                            \
      gld16(Wbase + (size_t)(i*16 + srow)*512 + (KB) + swz8, &Bs[(P)^1][w][i*512]);        \
    __builtin_amdgcn_sched_barrier(0);                                                     \
    if (DOLOAD){                                                                           \
      LD0 = *(const float4*)(aptr + (KA));                                                 \
      LD1 = *(const float4*)(aptr + (KA) + 4);                                             \
    }                                                                                      \
    __builtin_amdgcn_sched_barrier(0);                                                     \
    { V8 o;                                                                                \
      o.u[0]=f2b((CV0).x); o.u[1]=f2b((CV0).y); o.u[2]=f2b((CV0).z); o.u[3]=f2b((CV0).w); \
      o.u[4]=f2b((CV1).x); o.u[5]=f2b((CV1).y); o.u[6]=f2b((CV1).z); o.u[7]=f2b((CV1).w); \
      *(uint4*)&As[(P)^1][arow*32 + swz8] = o.q; }                                         \
    __builtin_amdgcn_s_setprio(1);                                                         \
    _Pragma("unroll")                                                                      \
    for (int mt = 0; mt < 4; mt++){                                                        \
      _Pragma("unroll")                                                                    \
      for (int nt = 0; nt < 8; nt++)                                                       \
        acc[mt][nt] = __builtin_amdgcn_mfma_f32_16x16x32_bf16(aF[mt], bF[nt], acc[mt][nt], 0, 0, 0); \
    }                                                                                      \
    __builtin_amdgcn_s_setprio(0);                                                         \
    asm volatile("s_waitcnt vmcnt(" #VMC ")" ::: "memory");                                \
    asm volatile("s_waitcnt lgkmcnt(0)" ::: "memory");                                     \
    __builtin_amdgcn_sched_barrier(0);                                                     \
    __builtin_amdgcn_s_barrier();                                                          \
  } while(0)

  for (int tt = 0; tt < 7; ++tt){
    PBODY(0, s1a, s1b, s0a, s0b, (2*tt+2)*32, (2*tt+1)*32, 1, 2);   // t = 2tt
    PBODY(1, s0a, s0b, s1a, s1b, (2*tt+3)*32, (2*tt+2)*32, 1, 2);   // t = 2tt+1
  }
  PBODY(0, s1a, s1b, s0a, s0b, 0, 480, 0, 0);                       // t = 14 (full drain)
  {                                                                  // t = 15, bare
    bf16x8 aF[4], bF[8];
    #pragma unroll
    for (int mt = 0; mt < 4; mt++)
      aF[mt] = *(const bf16x8*)&As[1][(mt*16 + lr)*32 + aqs8];
    #pragma unroll
    for (int nt = 0; nt < 8; nt++)
      bF[nt] = *(const bf16x8*)&Bs[1][w][(nt*16 + lr)*32 + aqs8];
    __builtin_amdgcn_s_setprio(1);
    #pragma unroll
    for (int mt = 0; mt < 4; mt++){
      #pragma unroll
      for (int nt = 0; nt < 8; nt++)
        acc[mt][nt] = __builtin_amdgcn_mfma_f32_16x16x32_bf16(aF[mt], bF[nt], acc[mt][nt], 0, 0, 0);
    }
    __builtin_amdgcn_s_setprio(0);
  }
#undef PBODY

  // ---- epilogue ----
  float wgv[8];
  if (y == 0){
    #pragma unroll
    for (int nt = 0; nt < 8; nt++) wgv[nt] = wg[wn + nt*16 + lr];
  }
  #pragma unroll
  for (int nt = 0; nt < 8; nt++){
    float bcol = bias[wn + nt*16 + lr];
    #pragma unroll
    for (int mt = 0; mt < 4; mt++)
      #pragma unroll
      for (int r = 0; r < 4; r++)
        acc[mt][nt][r] += bcol;
  }
  float ss[4][4], dq[4][4];
  #pragma unroll
  for (int mt = 0; mt < 4; mt++)
    #pragma unroll
    for (int r = 0; r < 4; r++){
      float s = 0.f, d = 0.f;
      #pragma unroll
      for (int nt = 0; nt < 8; nt++){
        float v = acc[mt][nt][r];
        s += v*v;
        if (y == 0) d += v * wgv[nt];
      }
      ss[mt][r] = s; dq[mt][r] = d;
    }
  #pragma unroll
  for (int off = 1; off < 16; off <<= 1){
    #pragma unroll
    for (int mt = 0; mt < 4; mt++)
      #pragma unroll
      for (int r = 0; r < 4; r++){
        ss[mt][r] += __shfl_xor(ss[mt][r], off, 64);
        if (y == 0) dq[mt][r] += __shfl_xor(dq[mt][r], off, 64);
      }
  }
  __syncthreads();                 // As dead -> reuse as f32 scratch
  float* red    = (float*)As;      // [4][64]
  float* red2   = red + 256;       // [4][64]
  float* rnS    = red2 + 256;      // [64]
  float* araw_s = rnS + 64;        // [64]  (total 2560B < 8KB As)
  if (lr == 0){
    #pragma unroll
    for (int mt = 0; mt < 4; mt++)
      #pragma unroll
      for (int r = 0; r < 4; r++){
        int row = mt*16 + quad*4 + r;
        red[w*64 + row] = ss[mt][r];
        if (y == 0) red2[w*64 + row] = dq[mt][r];
      }
  }
  __syncthreads();
  if (tid < 64){
    float t2 = red[tid] + red[64+tid] + red[128+tid] + red[192+tid];
    float rn = 1.f / fmaxf(sqrtf(t2), 1e-12f);
    rnS[tid] = rn;
    if (y == 0){
      float d = red2[tid] + red2[64+tid] + red2[128+tid] + red2[192+tid];
      float a = d * rn * 0.0625f;               // SCALE = 1/16
      araw_s[tid] = a;
      Araw[zi*32768 + m0 + tid] = a;
    }
  }
  __syncthreads();
  float part[8] = {};
  #pragma unroll
  for (int mt = 0; mt < 4; mt++){
    f32x4 rn4 = *(const f32x4*)&rnS[mt*16 + quad*4];
    #pragma unroll
    for (int r = 0; r < 4; r++){
      float aw = (y == 0) ? araw_s[mt*16 + quad*4 + r] : 0.f;
      #pragma unroll
      for (int nt = 0; nt < 8; nt++){
        float v = acc[mt][nt][r] * rn4[r];
        OUT[(size_t)(m0 + mt*16 + quad*4 + r)*512 + wn + nt*16 + lr] = f2b(v);
        if (y == 0) part[nt] += aw * v;
      }
    }
  }
  if (y == 0){
    #pragma unroll
    for (int nt = 0; nt < 8; nt++){
      part[nt] += __shfl_xor(part[nt], 16, 64);
      part[nt] += __shfl_xor(part[nt], 32, 64);
    }
    if (quad == 0){
      int bb = blockIdx.x >> 6;   // 64 rows/block, 4096 rows/batch
      #pragma unroll
      for (int nt = 0; nt < 8; nt++)
        atomicAdd(&Gun[((size_t)zi*8 + bb)*512 + wn + nt*16 + lr], part[nt]);
    }
  }
}

// ------------- MFMA GEMM, 128x128 tile, BK=32: 3-ring counted-vmcnt pipeline + T2 swizzle ------
// 3 LDS buffers (48 KB) at launch_bounds(256,3) -> 3 blocks/CU (vs R5's 64 KB / 2 blocks).
// Distance-2 prefetch; steady vmcnt(4) (tile t+1's 4 gld16 drained, t+2's in flight), raw
// s_barrier. Clamped dummy stage at t=NT-2 keeps counts uniform; drained before epilogue.
// MODE 2 adds XCD-bijective m-block swizzle (256 blocks % 8 == 0): each XCD owns one batch
// -> its 1 MB WT[b] slab stays L2-resident.
// MODE 1 (SMALL): C = A0 @ BT_z^T      K=512, N=512, z-batched over 4 slabs -> pfT (bf16)
// MODE 2 (FINAL): C = [kI|kM|qI|qM] @ WT[b]^T + cb  K=2048, N=256 -> Cf (f32)
template<int MODE>
__global__ __launch_bounds__(256, 3) void gemm2_k(
    const u16* __restrict__ A0, const u16* __restrict__ A1,
    const u16* __restrict__ A2, const u16* __restrict__ A3,
    const u16* __restrict__ BT,
    const float* __restrict__ cb,
    u16* __restrict__ Cq, float* __restrict__ Cf)
{
  constexpr int KTOT = (MODE == 2) ? 2048 : 512;
  constexpr int NT   = KTOT / 32;
  const int tid = threadIdx.x, l = tid & 63, w = tid >> 6;
  int bx = blockIdx.x;
  if constexpr (MODE == 2)
    bx = ((blockIdx.x & 7) << 5) | (blockIdx.x >> 3);   // XCD-bijective (256 % 8 == 0)
  const int m0 = bx * 128, n0 = blockIdx.y * 128;
  __shared__ __align__(16) u16 S[3][2][4096];   // 48 KB: [buf][A/B][128 rows x 32 k], swizzled
  f32x4 acc[4][4] = {};
  const int wm = (w >> 1) * 64, wn = (w & 1) * 64;
  const int lr = l & 15, quad = l >> 4;
  const int srow = l >> 2;
  const int swz8 = ((l & 3) ^ ((l >> 3) & 3)) * 8;     // stage slot (global pre-swizzle)
  const int aqs8 = (quad ^ ((lr >> 1) & 3)) * 8;       // read slot

  const u16* Bbase = BT;
  u16* Cqb = Cq;
  if constexpr (MODE == 2)
    Bbase = BT + (size_t)(m0 >> 12) * 256 * 2048;   // per-batch folded weights
  if constexpr (MODE == 1){
    Bbase = BT + (size_t)blockIdx.z * 262144;       // pcat slab
    Cqb   = Cq + (size_t)blockIdx.z * 131072;       // pfT slab
  }

  // stage tile at k-offset kk into ring buffer buf (4 gld16/wave), global col pre-swizzled
  auto stage = [&](int kk, int buf) __attribute__((always_inline)) {
    const u16* Ab; int kloc;
    if constexpr (MODE == 2){
      int which = kk >> 9; kloc = kk & 511;
      Ab = (which == 0) ? A0 : (which == 1) ? A1 : (which == 2) ? A2 : A3;
    } else { Ab = A0; kloc = kk; }
    #pragma unroll
    for (int i = 0; i < 2; i++){
      int r = w*32 + i*16 + srow;
      gld16(Ab    + (size_t)(m0 + r) * 512  + kloc + swz8, &S[buf][0][(w*2 + i)*512]);
      gld16(Bbase + (size_t)(n0 + r) * KTOT + kk   + swz8, &S[buf][1][(w*2 + i)*512]);
    }
  };

  // ---- prologue: stage tiles 0,1 ----
  stage(0, 0);
  stage(32, 1);
  asm volatile("s_waitcnt vmcnt(4)" ::: "memory");   // tile 0 landed; tile 1 in flight
  __builtin_amdgcn_sched_barrier(0);
  __builtin_amdgcn_s_barrier();

  int bc = 0;                        // buffer of tile t
  for (int t = 0; t < NT; ++t){
    const u16* Sc = &S[bc][0][0];
    bf16x8 aF[4], bF[4];
    #pragma unroll
    for (int mt = 0; mt < 4; mt++)
      aF[mt] = *(const bf16x8*)&Sc[(wm + mt*16 + lr)*32 + aqs8];
    #pragma unroll
    for (int nt = 0; nt < 4; nt++)
      bF[nt] = *(const bf16x8*)&Sc[4096 + (wn + nt*16 + lr)*32 + aqs8];
    if (t < NT - 1){
      int kn = (t + 2 < NT) ? (t + 2)*32 : 0;        // clamped dummy keeps counts uniform
      int bs = bc + 2; if (bs >= 3) bs -= 3;         // (t+2) % 3
      stage(kn, bs);
    }
    __builtin_amdgcn_s_setprio(1);
    #pragma unroll
    for (int mt = 0; mt < 4; mt++){
      #pragma unroll
      for (int nt = 0; nt < 4; nt++)
        acc[mt][nt] = __builtin_amdgcn_mfma_f32_16x16x32_bf16(aF[mt], bF[nt], acc[mt][nt], 0, 0, 0);
    }
    __builtin_amdgcn_s_setprio(0);
    if (t < NT - 1){
      __builtin_amdgcn_sched_barrier(0);
      asm volatile("s_waitcnt vmcnt(4)" ::: "memory"); // tile t+1 landed; t+2 in flight
      __builtin_amdgcn_sched_barrier(0);
      __builtin_amdgcn_s_barrier();
    }
    bc = (bc == 2) ? 0 : bc + 1;
  }
  asm volatile("s_waitcnt vmcnt(0)" ::: "memory");     // drain dummy gld16 before LDS dealloc

  #pragma unroll
  for (int nt = 0; nt < 4; nt++){
    int col = n0 + wn + nt*16 + lr;
    #pragma unroll
    for (int mt = 0; mt < 4; mt++){
      int row0 = m0 + wm + mt*16 + quad*4;
      #pragma unroll
      for (int r = 0; r < 4; r++){
        int row = row0 + r;
        float v = acc[mt][nt][r];
        if constexpr (MODE == 1){
          Cqb[(size_t)row*512 + col] = f2b(v);
        } else {
          Cf[(size_t)row*256 + col] = v + cb[col];
        }
      }
    }
  }
}

// -------- rA[i] = 1/max(||Araw_i||, eps), i = wsel*8 + b --------
__global__ __launch_bounds__(256) void ranorm_k(const float* __restrict__ Araw,
                                                float* __restrict__ rA){
  int idx = blockIdx.x;               // 0..15
  const float* A = Araw + idx*4096;
  int tid = threadIdx.x, l = tid & 63, w = tid >> 6;
  float ss = 0.f;
  for (int i = tid; i < 4096; i += 256){ float a = A[i]; ss += a*a; }
  #pragma unroll
  for (int off = 32; off > 0; off >>= 1) ss += __shfl_xor(ss, off, 64);
  __shared__ float red[4];
  if (l == 0) red[w] = ss;
  __syncthreads();
  if (tid == 0)
    rA[idx] = 1.f / fmaxf(sqrtf(red[0] + red[1] + red[2] + red[3]), 1e-12f);
}

// -------- WT[b][o][k]: k<512: G_I.pf1+G_M.pf4 (kI); <1024: G_I.pf2+G_M.pf3 (kM); else fT (qI+qM) --------
__global__ __launch_bounds__(256) void weff_k(
    const u16* __restrict__ pfT, const u16* __restrict__ fT,
    const float* __restrict__ Gun, const float* __restrict__ rA,
    u16* __restrict__ WT)
{
  int b = blockIdx.x, o = blockIdx.y, tid = threadIdx.x;
  int k0 = tid * 8;
  V8 out;
  if (k0 < 1024){
    int kk = k0 & 511;
    const u16* pa = pfT + ((k0 < 512) ? 0      : 131072) + o*512 + kk;  // pf1 / pf2
    const u16* pb = pfT + ((k0 < 512) ? 393216 : 262144) + o*512 + kk;  // pf4 / pf3
    float rI = rA[b], rM = rA[8 + b];
    const float* gI = Gun + b*512 + kk;
    const float* gM = Gun + 4096 + b*512 + kk;
    V8 Pa, Pb; Pa.q = *(const uint4*)pa; Pb.q = *(const uint4*)pb;
    float4 gi0 = *(const float4*)gI, gi1 = *(const float4*)(gI+4);
    float4 gm0 = *(const float4*)gM, gm1 = *(const float4*)(gM+4);
    float gi[8] = {gi0.x,gi0.y,gi0.z,gi0.w,gi1.x,gi1.y,gi1.z,gi1.w};
    float gm[8] = {gm0.x,gm0.y,gm0.z,gm0.w,gm1.x,gm1.y,gm1.z,gm1.w};
    #pragma unroll
    for (int j = 0; j < 8; j++)
      out.u[j] = f2b(rI*gi[j]*b2f(Pa.u[j]) + rM*gm[j]*b2f(Pb.u[j]));
  } else {
    out.q = *(const uint4*)(fT + o*512 + (k0 & 511));
  }
  *(uint4*)(WT + ((size_t)b*256 + o)*2048 + k0) = out.q;
}

extern "C" void kernel_launch(void* const* d_in, const int* in_sizes, int n_in,
                              void* d_out, int out_size, void* d_ws, size_t ws_size,
                              hipStream_t stream)
{
  const float* x_I  = (const float*)d_in[0];
  const float* x_M  = (const float*)d_in[1];
  const float* wq_I = (const float*)d_in[2];
  const float* bq_I = (const float*)d_in[3];
  const float* wk_I = (const float*)d_in[4];
  const float* bk_I = (const float*)d_in[5];
  const float* wq_M = (const float*)d_in[6];
  const float* bq_M = (const float*)d_in[7];
  const float* wk_M = (const float*)d_in[8];
  const float* bk_M = (const float*)d_in[9];
  const float* wg_I = (const float*)d_in[10];
  const float* wg_M = (const float*)d_in[11];
  const float* p1_w = (const float*)d_in[12];
  const float* p1_b = (const float*)d_in[13];
  const float* p2_w = (const float*)d_in[14];
  const float* p2_b = (const float*)d_in[15];
  const float* p3_w = (const float*)d_in[16];
  const float* p3_b = (const float*)d_in[17];
  const float* p4_w = (const float*)d_in[18];
  const float* p4_b = (const float*)d_in[19];
  const float* f_w  = (const float*)d_in[20];
  const float* f_b  = (const float*)d_in[21];

  char* ws = (char*)d_ws;
  u16*  wqkT_I = (u16*)(ws + 0);          // [1024][512] bf16
  u16*  wqkT_M = (u16*)(ws + 1048576);    // [1024][512]
  u16*  fT     = (u16*)(ws + 2097152);    // [256][512]
  u16*  pcat   = (u16*)(ws + 2359296);    // [4][512][512] bf16 straight
  u16*  pfT    = (u16*)(ws + 4456448);    // [4][256][512] bf16 (131072 elems/slab)
  u16*  WT     = (u16*)(ws + 5505024);    // [8][256][2048] bf16
  float* cb    = (float*)(ws + 13893632); // [256]
  float* Araw  = (float*)(ws + 13894656); // [2][32768]
  float* rA    = (float*)(ws + 14156800); // [16]
  float* Gun   = (float*)(ws + 14157056); // [2][8][512]
  u16*  qIb    = (u16*)(ws + 14189824);   // [32768][512] bf16 each
  u16*  kIb    = (u16*)(ws + 47744256);
  u16*  qMb    = (u16*)(ws + 81298688);
  u16*  kMb    = (u16*)(ws + 114853120);

  // --- 1: weight transposes + cbias + Gun zero + p1..p4 f32->bf16 (fused, one launch) ---
  TArgs t;
  CArgs c;
  const float* tsrc[5] = {wq_I, wk_I, wq_M, wk_M, f_w};
  u16* tdst[5] = {wqkT_I, wqkT_I + 262144, wqkT_M, wqkT_M + 262144, fT};
  int tnc[5] = {512, 512, 512, 512, 256};
  for (int i = 0; i < 5; i++){ t.src[i] = tsrc[i]; t.dst[i] = tdst[i]; t.ncol[i] = tnc[i]; }
  const float* csrc[4] = {p1_w, p2_w, p3_w, p4_w};
  u16* cdst[4] = {pcat, pcat + 262144, pcat + 524288, pcat + 786432};
  for (int i = 0; i < 4; i++){ c.src[i] = csrc[i]; c.dst[i] = cdst[i]; }
  transpose_k<<<dim3(8,8,10), 256, 0, stream>>>(t, c, p1_b, p2_b, p3_b, p4_b,
                                                f_w, f_b, cb, Gun);

  // --- 2: pfT_i[o][d] = sum_j f_w[j][o] p_i[d][j] ---
  gemm2_k<1><<<dim3(2,4,4), 256, 0, stream>>>(fT, nullptr, nullptr, nullptr,
      pcat, nullptr, pfT, nullptr);

  // --- 3: fused projection + norm + Araw + Gun (both inputs, one launch) ---
  proj_k<<<dim3(512,2,2), 256, 0, stream>>>(x_I, x_M, wqkT_I, wqkT_M,
      bq_I, bk_I, bq_M, bk_M, wg_I, wg_M, qIb, kIb, qMb, kMb, Araw, Gun);

  // --- 4: rA ---
  ranorm_k<<<16, 256, 0, stream>>>(Araw, rA);

  // --- 5: fold G into effective weights ---
  weff_k<<<dim3(8,256), 256, 0, stream>>>(pfT, fT, Gun, rA, WT);

  // --- 6: out = [kI|kM|qI|qM] @ WT[b]^T + cb ---
  gemm2_k<2><<<dim3(256,2), 256, 0, stream>>>(kIb, kMb, qIb, qMb,
      WT, cb, nullptr, (float*)d_out);
}